// Round 11
// baseline (182.237 us; speedup 1.0000x reference)
//
#include <hip/hip_runtime.h>
#include <cstdint>
#include <cstddef>

namespace {

constexpr int kB = 16;
constexpr int kH = 512;
constexpr int kW = 512;
constexpr int kHW = kH * kW;
constexpr int kNS = 37632;     // NUM_POINTS * OVERSAMPLE
constexpr int kNS4 = kNS / 4;  // 9408
constexpr int kNUNC = 9408;
constexpr int kNRAND = 3136;
constexpr int kNPTS = 12544;
constexpr int kBins = 16384;   // exp(8)+mant(6) bins of |z|
constexpr int kBXB = 16;       // bbox partial blocks per batch
constexpr int kRPB = 4;        // rand-point blocks per batch
constexpr int kSLB = 16;       // slices per batch in K2 (os-CE + region)
constexpr int kSlicePts = kNS / kSLB;   // 2352
constexpr int kSlice4 = kSlicePts / 4;  // 588
constexpr int kPairs = kNS / 2;
constexpr int kSampSlots = 148;
constexpr int kSampleBlocks = 8 * kSampSlots;    // 1184
constexpr int kBboxBlocks = kB * kBXB;           // 256
constexpr int kRandBlocks = kB * kRPB;           // 64
constexpr int kCAP = 2048;

// workspace layout (bytes)
constexpr size_t OFF_PZ   = 0;                                     // [B][NS] u32 signed z bits
constexpr size_t OFF_TV   = OFF_PZ + (size_t)kB * kNS * 4;         // [B][NS] f32 gt label
constexpr size_t OFF_GH   = OFF_TV + (size_t)kB * kNS * 4;         // [B][16384] u32 global hist
constexpr size_t OFF_BBP  = OFF_GH + (size_t)kB * kBins * 4;       // [B][16][4] i32
constexpr size_t OFF_PLP  = OFF_BBP + (size_t)kB * kBXB * 4 * 4;   // [B][4][4] f32 rand partials
constexpr size_t OFF_OSP2 = OFF_PLP + (size_t)kB * kRPB * 4 * 4;   // [B][16][4] f32 os slice sums
constexpr size_t OFF_RGP  = OFF_OSP2 + (size_t)kB * kSLB * 4 * 4;  // [B][16][5] f32 region partials
constexpr size_t OFF_CAND = OFF_RGP + (size_t)kB * kSLB * 5 * 4;   // [B][2048] i32
constexpr size_t OFF_CCNT = OFF_CAND + (size_t)kB * kCAP * 4;      // [B] i32 (pad 64)
constexpr size_t OFF_BNFO = OFF_CCNT + 256;                        // [B][2] i32 (bstar, need)

} // namespace

__device__ __forceinline__ float sample_bilinear(const float* __restrict__ img,
                                                 float cx, float cy) {
  float x = cx * (float)kW - 0.5f;
  float y = cy * (float)kH - 0.5f;
  float x0f = floorf(x), y0f = floorf(y);
  float wx1 = x - x0f, wx0 = 1.0f - wx1;
  float wy1 = y - y0f, wy0 = 1.0f - wy1;
  int x0 = (int)x0f, y0 = (int)y0f;
  int x1 = x0 + 1, y1 = y0 + 1;
  int xc0 = min(max(x0, 0), kW - 1), xc1 = min(max(x1, 0), kW - 1);
  int yc0 = min(max(y0, 0), kH - 1), yc1 = min(max(y1, 0), kH - 1);
  float v00 = ((x0 >= 0) && (x0 < kW) && (y0 >= 0) && (y0 < kH)) ? img[yc0 * kW + xc0] : 0.0f;
  float v01 = ((x1 >= 0) && (x1 < kW) && (y0 >= 0) && (y0 < kH)) ? img[yc0 * kW + xc1] : 0.0f;
  float v10 = ((x0 >= 0) && (x0 < kW) && (y1 >= 0) && (y1 < kH)) ? img[yc1 * kW + xc0] : 0.0f;
  float v11 = ((x1 >= 0) && (x1 < kW) && (y1 >= 0) && (y1 < kH)) ? img[yc1 * kW + xc1] : 0.0f;
  return v00 * (wy0 * wx0) + v01 * (wy0 * wx1) + v10 * (wy1 * wx0) + v11 * (wy1 * wx1);
}

__device__ __forceinline__ void ce_pair(float z, float tt, float& ce, float& p) {
  float a = expf(-fabsf(z));
  ce = fmaxf(z, 0.0f) - z * tt + log1pf(a);
  float inv = 1.0f / (1.0f + a);
  p = (z >= 0.0f) ? inv : a * inv;
}

// ---- K0: zero global hist + candidate counters (every call; deterministic) ----
__global__ __launch_bounds__(1024) void zero_kernel(unsigned* __restrict__ gh,
                                                    int* __restrict__ ccnt) {
  int idx = blockIdx.x * 1024 + threadIdx.x;
  if (idx < kB * kBins) gh[idx] = 0u;
  if (blockIdx.x == 0 && threadIdx.x < kB) ccnt[threadIdx.x] = 0;
}

// ---- K1: os sampling (z,t out + hist atomics) | bbox | rand CE; XCD-clustered ----
__global__ __launch_bounds__(256) void fused1_kernel(const float* __restrict__ pred,
                                                     const float* __restrict__ gt,
                                                     const float* __restrict__ coords_os,
                                                     const float* __restrict__ coords_rand,
                                                     unsigned* __restrict__ pz,
                                                     float* __restrict__ tv,
                                                     unsigned* __restrict__ gh,
                                                     int* __restrict__ bbp,
                                                     float* __restrict__ plp) {
  int blk = blockIdx.x;
  int t = threadIdx.x;

  if (blk < kSampleBlocks) {
    int x = blk & 7;
    int s = blk >> 3;                 // 0..147
    int b = x * 2 + (s & 1);
    int chunk = s >> 1;               // 0..73
    int pib = chunk * 256 + t;
    if (pib >= kPairs) return;
    size_t gp = (size_t)b * kPairs + pib;
    float4 c2 = ((const float4*)coords_os)[gp];
    size_t i0 = gp * 2;
    const float* pred_b = pred + (size_t)b * kHW;
    const float* gt_b = gt + (size_t)b * kHW;
    float z0 = sample_bilinear(pred_b, c2.x, c2.y);
    float z1 = sample_bilinear(pred_b, c2.z, c2.w);
    float t0 = sample_bilinear(gt_b, c2.x, c2.y);
    float t1 = sample_bilinear(gt_b, c2.z, c2.w);
    unsigned u0 = __float_as_uint(z0), u1 = __float_as_uint(z1);
    *(uint2*)&pz[i0] = make_uint2(u0, u1);
    *(float2*)&tv[i0] = make_float2(t0, t1);
    unsigned* gh_b = gh + (size_t)b * kBins;
    atomicAdd(&gh_b[(u0 & 0x7fffffffu) >> 17], 1u);
    atomicAdd(&gh_b[(u1 & 0x7fffffffu) >> 17], 1u);
    return;
  }

  if (blk < kSampleBlocks + kBboxBlocks) {
    __shared__ int r0[256], r1[256], r2[256], r3[256];
    int i = blk - kSampleBlocks;
    int x = i & 7;
    int s = i >> 3;                   // 0..31
    int b = x * 2 + (s & 1);
    int c = s >> 1;                   // 0..15
    constexpr int CHUNK4 = kHW / kBXB / 4;  // 4096 float4
    const float4* pred4 = (const float4*)(pred + (size_t)b * kHW) + (size_t)c * CHUNK4;
    int pbase = c * CHUNK4 * 4;
    int xmn = kW, xmx = -1, ymn = kH, ymx = -1;
    for (int i4 = t; i4 < CHUNK4; i4 += 256) {
      float4 z = pred4[i4];
      int p = pbase + i4 * 4;
      int y = p >> 9;
      int x0 = p & (kW - 1);
      if (z.x > 0.0f) { xmn = min(xmn, x0);     xmx = max(xmx, x0);     ymn = min(ymn, y); ymx = max(ymx, y); }
      if (z.y > 0.0f) { xmn = min(xmn, x0 + 1); xmx = max(xmx, x0 + 1); ymn = min(ymn, y); ymx = max(ymx, y); }
      if (z.z > 0.0f) { xmn = min(xmn, x0 + 2); xmx = max(xmx, x0 + 2); ymn = min(ymn, y); ymx = max(ymx, y); }
      if (z.w > 0.0f) { xmn = min(xmn, x0 + 3); xmx = max(xmx, x0 + 3); ymn = min(ymn, y); ymx = max(ymx, y); }
    }
    r0[t] = xmn; r1[t] = xmx; r2[t] = ymn; r3[t] = ymx;
    __syncthreads();
    for (int s2 = 128; s2 > 0; s2 >>= 1) {
      if (t < s2) {
        r0[t] = min(r0[t], r0[t + s2]);
        r1[t] = max(r1[t], r1[t + s2]);
        r2[t] = min(r2[t], r2[t + s2]);
        r3[t] = max(r3[t], r3[t + s2]);
      }
      __syncthreads();
    }
    if (t == 0) {
      int* o = bbp + ((size_t)b * kBXB + c) * 4;
      o[0] = r0[0]; o[1] = r1[0]; o[2] = r2[0]; o[3] = r3[0];
    }
    return;
  }

  // rand-point CE partials
  {
    __shared__ float red[4][256];
    int i = blk - kSampleBlocks - kBboxBlocks;
    int x = i & 7;
    int s = i >> 3;                   // 0..7
    int b = x * 2 + (s & 1);
    int c = s >> 1;                   // 0..3
    const float* pred_b = pred + (size_t)b * kHW;
    const float* gt_b = gt + (size_t)b * kHW;
    float ce_s = 0.0f, p_s = 0.0f, t_s = 0.0f, pt_s = 0.0f;
    for (int e = c * 256 + t; e < kNRAND; e += kRPB * 256) {
      float2 cc = *(const float2*)&coords_rand[((size_t)b * kNRAND + e) * 2];
      float z = sample_bilinear(pred_b, cc.x, cc.y);
      float tt = sample_bilinear(gt_b, cc.x, cc.y);
      float ce, p;
      ce_pair(z, tt, ce, p);
      ce_s += ce; p_s += p; t_s += tt; pt_s += p * tt;
    }
    red[0][t] = ce_s; red[1][t] = p_s; red[2][t] = t_s; red[3][t] = pt_s;
    __syncthreads();
    for (int s2 = 128; s2 > 0; s2 >>= 1) {
      if (t < s2) {
        red[0][t] += red[0][t + s2];
        red[1][t] += red[1][t + s2];
        red[2][t] += red[2][t + s2];
        red[3][t] += red[3][t + s2];
      }
      __syncthreads();
    }
    if (t == 0) {
      float* o = plp + ((size_t)b * kRPB + c) * 4;
      o[0] = red[0][0]; o[1] = red[1][0]; o[2] = red[2][0]; o[3] = red[3][0];
    }
  }
}

// ---- K2: 256 blocks; each does region chunk + hist scan + os-CE slice ----
__global__ __launch_bounds__(1024) void fused2_kernel(const unsigned* __restrict__ pz,
                                                      const float* __restrict__ tv,
                                                      const float* __restrict__ pred,
                                                      const float* __restrict__ gt,
                                                      const unsigned* __restrict__ gh,
                                                      const int* __restrict__ bbp,
                                                      float* __restrict__ osp2,
                                                      float* __restrict__ rgp,
                                                      int* __restrict__ cand,
                                                      int* __restrict__ ccnt,
                                                      int* __restrict__ binfo) {
  __shared__ unsigned sums[1024];
  __shared__ int s_bstar, s_need;
  int blk = blockIdx.x;
  int t = threadIdx.x;
  int x = blk & 7;
  int s = blk >> 3;                 // 0..31
  int b = x * 2 + (s & 1);          // XCD-clustered: batch b on XCD b/2
  int c = s >> 1;                   // 0..15

  // ---- region chunk (HBM stream; issue first) ----
  {
    constexpr int CHUNK4 = kHW / kSLB / 4;  // 4096 float4
    const float4* pred4 = (const float4*)(pred + (size_t)b * kHW) + (size_t)c * CHUNK4;
    const float4* gt4 = (const float4*)(gt + (size_t)b * kHW) + (size_t)c * CHUNK4;
    int xmn = kW, xmx = -1, ymn = kH, ymx = -1;
#pragma unroll
    for (int u = 0; u < kBXB; ++u) {
      const int4 pb = *(const int4*)(bbp + ((size_t)b * kBXB + u) * 4);
      xmn = min(xmn, pb.x); xmx = max(xmx, pb.y);
      ymn = min(ymn, pb.z); ymx = max(ymx, pb.w);
    }
    bool empty = (xmx < 0);
    int x1 = empty ? 0 : xmn;
    int x2 = min(empty ? (kW - 1) : xmx, kW - 1);
    int y1 = empty ? 0 : ymn;
    int y2 = min(empty ? (kH - 1) : ymx, kH - 1);
    bool valid = (x2 > x1) && (y2 > y1);

    int pbase = c * CHUNK4 * 4;
    float wsum = 0.0f, bcew = 0.0f, inter = 0.0f, pw = 0.0f, gw = 0.0f;
    for (int i4 = t; i4 < CHUNK4; i4 += 1024) {
      float4 zv = pred4[i4];
      float4 gv = gt4[i4];
      int p = pbase + i4 * 4;
      int y = p >> 9;
      int x0 = p & (kW - 1);
      bool iny = valid && (y >= y1) && (y <= y2);
#pragma unroll
      for (int l = 0; l < 4; ++l) {
        float z = (l == 0) ? zv.x : (l == 1) ? zv.y : (l == 2) ? zv.z : zv.w;
        float g = (l == 0) ? gv.x : (l == 1) ? gv.y : (l == 2) ? gv.z : gv.w;
        int xx = x0 + l;
        float w = (iny && xx >= x1 && xx <= x2) ? 2.0f : 0.5f;
        float a = expf(-fabsf(z));
        float sp = fmaxf(-z, 0.0f) + log1pf(a);
        float bce = sp + (1.0f - g) * z;
        float inv = 1.0f / (1.0f + a);
        float pp = (z >= 0.0f) ? inv : a * inv;
        wsum += w;
        bcew += bce * w;
        inter += pp * g * w;
        pw += pp * w;
        gw += g * w;
      }
    }
    float* redf = (float*)sums;
    float vals[5] = {wsum, bcew, inter, pw, gw};
#pragma unroll
    for (int q5 = 0; q5 < 5; ++q5) {
      float v = vals[q5];
      for (int o = 32; o > 0; o >>= 1) v += __shfl_down(v, o, 64);
      if ((t & 63) == 0) redf[(t >> 6) * 5 + q5] = v;
    }
    __syncthreads();
    if (t == 0) {
      float o0 = 0, o1 = 0, o2 = 0, o3 = 0, o4 = 0;
      for (int w = 0; w < 16; ++w) {
        o0 += redf[w * 5 + 0]; o1 += redf[w * 5 + 1]; o2 += redf[w * 5 + 2];
        o3 += redf[w * 5 + 3]; o4 += redf[w * 5 + 4];
      }
      float* o = rgp + ((size_t)b * kSLB + c) * 5;
      o[0] = o0; o[1] = o1; o[2] = o2; o[3] = o3; o[4] = o4;
    }
    __syncthreads();
  }

  // ---- boundary search from global hist (r7-verified shfl hierarchy) ----
  {
    const unsigned* h = gh + (size_t)b * kBins;
    unsigned sloc = 0;
#pragma unroll
    for (int k = 0; k < 16; ++k) sloc += h[t * 16 + k];   // bins t*16..t*16+15
    sums[t] = sloc;
    __syncthreads();
    if (t < 64) {
      const unsigned K = (unsigned)kNUNC;
      unsigned v = 0;
#pragma unroll
      for (int k = 0; k < 16; ++k) v += sums[t * 16 + k]; // bins t*256..
      unsigned cum = v;
      for (int off = 1; off < 64; off <<= 1) {
        unsigned xx = __shfl_up(cum, off, 64);
        if (t >= off) cum += xx;
      }
      unsigned long long m = __ballot(cum >= K);
      int L = (int)__ffsll(m) - 1;
      unsigned base1 = __shfl(cum - v, L, 64);
      unsigned v2 = (t < 16) ? sums[L * 16 + t] : 0u;
      unsigned cum2 = v2;
      for (int off = 1; off < 16; off <<= 1) {
        unsigned xx = __shfl_up(cum2, off, 64);
        if (t >= off) cum2 += xx;
      }
      unsigned long long m2 = __ballot((t < 16) && (base1 + cum2 >= K));
      int M = (int)__ffsll(m2) - 1;
      unsigned base2 = __shfl(base1 + cum2 - v2, M, 64);
      int E = L * 16 + M;
      unsigned v3 = (t < 16) ? h[E * 16 + t] : 0u;
      unsigned cum3 = v3;
      for (int off = 1; off < 16; off <<= 1) {
        unsigned xx = __shfl_up(cum3, off, 64);
        if (t >= off) cum3 += xx;
      }
      unsigned long long m3 = __ballot((t < 16) && (base2 + cum3 >= K));
      int F = (int)__ffsll(m3) - 1;
      if (t == F) {
        s_bstar = E * 16 + F;
        s_need = (int)(K - (base2 + cum3 - v3));
      }
    }
    __syncthreads();
  }
  int bstar = s_bstar;
  int need = s_need;
  if (c == 0 && t == 0) { binfo[b * 2] = bstar; binfo[b * 2 + 1] = need; }

  // ---- os-CE slice: points [c*2352, (c+1)*2352), branchless accumulate ----
  {
    float ce_s = 0.0f, p_s = 0.0f, t_s = 0.0f, pt_s = 0.0f;
    if (t < kSlice4) {
      int g4 = b * kNS4 + c * kSlice4 + t;         // global uint4 index
      uint4 u = ((const uint4*)pz)[g4];
      float4 tt4 = ((const float4*)tv)[g4];
      int lbase = (c * kSlice4 + t) * 4;           // local point index in batch
#pragma unroll
      for (int e = 0; e < 4; ++e) {
        unsigned ub = (e == 0) ? u.x : (e == 1) ? u.y : (e == 2) ? u.z : u.w;
        float ttv = (e == 0) ? tt4.x : (e == 1) ? tt4.y : (e == 2) ? tt4.z : tt4.w;
        int bin = (int)((ub & 0x7fffffffu) >> 17);
        float z = __uint_as_float(ub);
        float ce, p;
        ce_pair(z, ttv, ce, p);
        float w = (bin < bstar) ? 1.0f : 0.0f;
        ce_s += w * ce; p_s += w * p; t_s += w * ttv; pt_s += w * p * ttv;
        if (bin == bstar) {
          int pos = atomicAdd(&ccnt[b], 1);
          if (pos < kCAP) cand[b * kCAP + pos] = lbase + e;
        }
      }
    }
    float* redf = (float*)sums;
    float vals[4] = {ce_s, p_s, t_s, pt_s};
#pragma unroll
    for (int q = 0; q < 4; ++q) {
      float v = vals[q];
      for (int o = 32; o > 0; o >>= 1) v += __shfl_down(v, o, 64);
      if ((t & 63) == 0) redf[(t >> 6) * 4 + q] = v;
    }
    __syncthreads();
    if (t == 0) {
      float o0 = 0, o1 = 0, o2 = 0, o3 = 0;
      for (int w = 0; w < 16; ++w) {
        o0 += redf[w * 4 + 0]; o1 += redf[w * 4 + 1];
        o2 += redf[w * 4 + 2]; o3 += redf[w * 4 + 3];
      }
      float* o = osp2 + ((size_t)b * kSLB + c) * 4;
      o[0] = o0; o[1] = o1; o[2] = o2; o[3] = o3;
    }
  }
}

// ---- K3: boundary rank (deterministic, index-ordered) + f64 finalize ----
__global__ __launch_bounds__(1024) void final_kernel(const unsigned* __restrict__ pz,
                                                     const float* __restrict__ tv,
                                                     const int* __restrict__ cand,
                                                     const int* __restrict__ ccnt,
                                                     const int* __restrict__ binfo,
                                                     const float* __restrict__ osp2,
                                                     const float* __restrict__ plp,
                                                     const float* __restrict__ rgp,
                                                     float* __restrict__ out) {
  __shared__ int scand[kCAP];
  __shared__ int ssort[kCAP];
  __shared__ unsigned usums[1024];
  __shared__ float redf[16 * 4];
  __shared__ float bsum[kB][4];
  __shared__ double shd[kB][4];
  __shared__ int s_round;
  int t = threadIdx.x;

  for (int b = 0; b < kB; ++b) {
    int bstar = binfo[b * 2];
    int need = binfo[b * 2 + 1];
    int c = ccnt[b];
    const unsigned* pz_b = pz + (size_t)b * kNS;
    const float* tv_b = tv + (size_t)b * kNS;
    float ce_s = 0.0f, p_s = 0.0f, t_s = 0.0f, pt_s = 0.0f;

    if (c <= kCAP) {
      for (int i = t; i < c; i += 1024) scand[i] = cand[b * kCAP + i];
      __syncthreads();
      for (int i = t; i < c; i += 1024) {
        int my = scand[i];
        int r = 0;
        for (int k = 0; k < c; ++k) r += (scand[k] < my) ? 1 : 0;
        ssort[r] = my;
      }
      __syncthreads();
      for (int r = t; r < need; r += 1024) {
        int my = ssort[r];
        float z = __uint_as_float(pz_b[my]);
        float ttv = tv_b[my];
        float ce, p;
        ce_pair(z, ttv, ce, p);
        ce_s += ce; p_s += p; t_s += ttv; pt_s += p * ttv;
      }
      __syncthreads();
    } else {
      // ordered-scan fallback over full batch (duplicate-heavy pathological data)
      if (t == 0) s_round = 0;
      __syncthreads();
      for (int j = 0; j < 10; ++j) {
        int idx4 = j * 1024 + t;
        unsigned meq = 0u;
        if (idx4 < kNS4) {
          uint4 u = ((const uint4*)pz_b)[idx4];
          meq = (unsigned)((int)((u.x & 0x7fffffffu) >> 17) == bstar) |
                ((unsigned)((int)((u.y & 0x7fffffffu) >> 17) == bstar) << 1) |
                ((unsigned)((int)((u.z & 0x7fffffffu) >> 17) == bstar) << 2) |
                ((unsigned)((int)((u.w & 0x7fffffffu) >> 17) == bstar) << 3);
        }
        unsigned cnt2 = __popc(meq);
        usums[t] = cnt2;
        __syncthreads();
        for (int off = 1; off < 1024; off <<= 1) {
          unsigned v = (t >= off) ? usums[t - off] : 0u;
          __syncthreads();
          usums[t] += v;
          __syncthreads();
        }
        int myBase = s_round + (int)(usums[t] - cnt2);
        unsigned mm = meq;
        while (mm) {
          int e = __ffs(mm) - 1;
          mm &= mm - 1;
          if (myBase < need) {
            int my = idx4 * 4 + e;
            float z = __uint_as_float(pz_b[my]);
            float ttv = tv_b[my];
            float ce, p;
            ce_pair(z, ttv, ce, p);
            ce_s += ce; p_s += p; t_s += ttv; pt_s += p * ttv;
          }
          myBase++;
        }
        __syncthreads();
        if (t == 0) s_round += (int)usums[1023];
        __syncthreads();
      }
    }

    // reduce 4 sums -> bsum[b]
    float vals[4] = {ce_s, p_s, t_s, pt_s};
#pragma unroll
    for (int q = 0; q < 4; ++q) {
      float v = vals[q];
      for (int o = 32; o > 0; o >>= 1) v += __shfl_down(v, o, 64);
      if ((t & 63) == 0) redf[(t >> 6) * 4 + q] = v;
    }
    __syncthreads();
    if (t == 0) {
      float o0 = 0, o1 = 0, o2 = 0, o3 = 0;
      for (int w = 0; w < 16; ++w) {
        o0 += redf[w * 4 + 0]; o1 += redf[w * 4 + 1];
        o2 += redf[w * 4 + 2]; o3 += redf[w * 4 + 3];
      }
      bsum[b][0] = o0; bsum[b][1] = o1; bsum[b][2] = o2; bsum[b][3] = o3;
    }
    __syncthreads();
  }

  // f64 finalize
  if (t < kB) {
    double ce = bsum[t][0], p = bsum[t][1], tt = bsum[t][2], pt = bsum[t][3];
    for (int c = 0; c < kSLB; ++c) {
      const float* q = osp2 + ((size_t)t * kSLB + c) * 4;
      ce += q[0]; p += q[1]; tt += q[2]; pt += q[3];
    }
    for (int c = 0; c < kRPB; ++c) {
      const float* q = plp + ((size_t)t * kRPB + c) * 4;
      ce += q[0]; p += q[1]; tt += q[2]; pt += q[3];
    }
    double ws = 0, bc = 0, in = 0, pw = 0, gw = 0;
    for (int c = 0; c < kSLB; ++c) {
      const float* q = rgp + ((size_t)t * kSLB + c) * 5;
      ws += q[0]; bc += q[1]; in += q[2]; pw += q[3]; gw += q[4];
    }
    shd[t][0] = ce / (double)kNPTS;
    shd[t][1] = 1.0 - (2.0 * pt + 1.0) / (p + tt + 1.0);
    double wss = ws > 1e-6 ? ws : 1e-6;
    shd[t][2] = bc / wss;
    shd[t][3] = 1.0 - (2.0 * in + 1.0) / (pw + gw + 1.0);
  }
  __syncthreads();
  if (t == 0) {
    double a = 0, b2 = 0, c2 = 0, d = 0;
    for (int i = 0; i < kB; ++i) { a += shd[i][0]; b2 += shd[i][1]; c2 += shd[i][2]; d += shd[i][3]; }
    out[0] = (float)(a / 16.0);
    out[1] = (float)(b2 / 16.0);
    out[2] = (float)(c2 / 16.0);
    out[3] = (float)(d / 16.0);
  }
}

extern "C" void kernel_launch(void* const* d_in, const int* in_sizes, int n_in,
                              void* d_out, int out_size, void* d_ws, size_t ws_size,
                              hipStream_t stream) {
  const float* pred = (const float*)d_in[0];
  const float* gt = (const float*)d_in[1];
  const float* coords_os = (const float*)d_in[2];
  const float* coords_rand = (const float*)d_in[3];
  float* out = (float*)d_out;
  char* ws = (char*)d_ws;

  unsigned* pz = (unsigned*)(ws + OFF_PZ);
  float* tv = (float*)(ws + OFF_TV);
  unsigned* gh = (unsigned*)(ws + OFF_GH);
  int* bbp = (int*)(ws + OFF_BBP);
  float* plp = (float*)(ws + OFF_PLP);
  float* osp2 = (float*)(ws + OFF_OSP2);
  float* rgp = (float*)(ws + OFF_RGP);
  int* cand = (int*)(ws + OFF_CAND);
  int* ccnt = (int*)(ws + OFF_CCNT);
  int* binfo = (int*)(ws + OFF_BNFO);

  zero_kernel<<<(kB * kBins + 1023) / 1024, 1024, 0, stream>>>(gh, ccnt);
  fused1_kernel<<<kSampleBlocks + kBboxBlocks + kRandBlocks, 256, 0, stream>>>(
      pred, gt, coords_os, coords_rand, pz, tv, gh, bbp, plp);
  fused2_kernel<<<kB * kSLB, 1024, 0, stream>>>(pz, tv, pred, gt, gh, bbp,
                                                osp2, rgp, cand, ccnt, binfo);
  final_kernel<<<1, 1024, 0, stream>>>(pz, tv, cand, ccnt, binfo, osp2, plp, rgp, out);
}

// Round 12
// 111.890 us; speedup vs baseline: 1.6287x; 1.6287x over previous
//
#include <hip/hip_runtime.h>
#include <cstdint>
#include <cstddef>

namespace {

constexpr int kB = 16;
constexpr int kH = 512;
constexpr int kW = 512;
constexpr int kHW = kH * kW;
constexpr int kNS = 37632;     // NUM_POINTS * OVERSAMPLE
constexpr int kNS4 = kNS / 4;  // 9408
constexpr int kNUNC = 9408;
constexpr int kNRAND = 3136;
constexpr int kNPTS = 12544;
constexpr int kBins = 16384;   // exp(8)+mant(6) bins of |z|
constexpr int kBXB = 16;       // bbox partial blocks per batch
constexpr int kRPB = 4;        // rand-point blocks per batch
constexpr int kSLB = 16;       // slices per batch in K2 (os-CE + region)
constexpr int kSlicePts = kNS / kSLB;   // 2352
constexpr int kSlice4 = kSlicePts / 4;  // 588
constexpr int kPairs = kNS / 2;
constexpr int kSampSlots = 148;
constexpr int kSampleBlocks = 8 * kSampSlots;    // 1184
constexpr int kBboxBlocks = kB * kBXB;           // 256
constexpr int kRandBlocks = kB * kRPB;           // 64
constexpr int kCAP = 2048;

// workspace layout (bytes)
constexpr size_t OFF_PZ   = 0;                                     // [B][NS] u32 signed z bits
constexpr size_t OFF_TV   = OFF_PZ + (size_t)kB * kNS * 4;         // [B][NS] f32 gt label
constexpr size_t OFF_GH   = OFF_TV + (size_t)kB * kNS * 4;         // [B][16384] u32 global hist
constexpr size_t OFF_BBP  = OFF_GH + (size_t)kB * kBins * 4;       // [B][16][4] i32
constexpr size_t OFF_PLP  = OFF_BBP + (size_t)kB * kBXB * 4 * 4;   // [B][4][4] f32 rand partials
constexpr size_t OFF_OSP2 = OFF_PLP + (size_t)kB * kRPB * 4 * 4;   // [B][16][4] f32 os slice sums
constexpr size_t OFF_RGP  = OFF_OSP2 + (size_t)kB * kSLB * 4 * 4;  // [B][16][5] f32 region partials
constexpr size_t OFF_CAND = OFF_RGP + (size_t)kB * kSLB * 5 * 4;   // [B][2048] i32
constexpr size_t OFF_CCNT = OFF_CAND + (size_t)kB * kCAP * 4;      // [B] i32 (pad 64)
constexpr size_t OFF_BNFO = OFF_CCNT + 256;                        // [B][2] i32 (bstar, need)
constexpr size_t OFF_BSUM = OFF_BNFO + 256;                        // [B][4] f32 boundary sums

} // namespace

__device__ __forceinline__ float sample_bilinear(const float* __restrict__ img,
                                                 float cx, float cy) {
  float x = cx * (float)kW - 0.5f;
  float y = cy * (float)kH - 0.5f;
  float x0f = floorf(x), y0f = floorf(y);
  float wx1 = x - x0f, wx0 = 1.0f - wx1;
  float wy1 = y - y0f, wy0 = 1.0f - wy1;
  int x0 = (int)x0f, y0 = (int)y0f;
  int x1 = x0 + 1, y1 = y0 + 1;
  int xc0 = min(max(x0, 0), kW - 1), xc1 = min(max(x1, 0), kW - 1);
  int yc0 = min(max(y0, 0), kH - 1), yc1 = min(max(y1, 0), kH - 1);
  float v00 = ((x0 >= 0) && (x0 < kW) && (y0 >= 0) && (y0 < kH)) ? img[yc0 * kW + xc0] : 0.0f;
  float v01 = ((x1 >= 0) && (x1 < kW) && (y0 >= 0) && (y0 < kH)) ? img[yc0 * kW + xc1] : 0.0f;
  float v10 = ((x0 >= 0) && (x0 < kW) && (y1 >= 0) && (y1 < kH)) ? img[yc1 * kW + xc0] : 0.0f;
  float v11 = ((x1 >= 0) && (x1 < kW) && (y1 >= 0) && (y1 < kH)) ? img[yc1 * kW + xc1] : 0.0f;
  return v00 * (wy0 * wx0) + v01 * (wy0 * wx1) + v10 * (wy1 * wx0) + v11 * (wy1 * wx1);
}

__device__ __forceinline__ void ce_pair(float z, float tt, float& ce, float& p) {
  float a = expf(-fabsf(z));
  ce = fmaxf(z, 0.0f) - z * tt + log1pf(a);
  float inv = 1.0f / (1.0f + a);
  p = (z >= 0.0f) ? inv : a * inv;
}

// ---- K0: zero global hist + candidate counters (every call; deterministic) ----
__global__ __launch_bounds__(1024) void zero_kernel(unsigned* __restrict__ gh,
                                                    int* __restrict__ ccnt) {
  int idx = blockIdx.x * 1024 + threadIdx.x;
  if (idx < kB * kBins) gh[idx] = 0u;
  if (blockIdx.x == 0 && threadIdx.x < kB) ccnt[threadIdx.x] = 0;
}

// ---- K1: os sampling (z,t out + hist atomics) | bbox | rand CE; XCD-clustered ----
__global__ __launch_bounds__(256) void fused1_kernel(const float* __restrict__ pred,
                                                     const float* __restrict__ gt,
                                                     const float* __restrict__ coords_os,
                                                     const float* __restrict__ coords_rand,
                                                     unsigned* __restrict__ pz,
                                                     float* __restrict__ tv,
                                                     unsigned* __restrict__ gh,
                                                     int* __restrict__ bbp,
                                                     float* __restrict__ plp) {
  int blk = blockIdx.x;
  int t = threadIdx.x;

  if (blk < kSampleBlocks) {
    int x = blk & 7;
    int s = blk >> 3;                 // 0..147
    int b = x * 2 + (s & 1);
    int chunk = s >> 1;               // 0..73
    int pib = chunk * 256 + t;
    if (pib >= kPairs) return;
    size_t gp = (size_t)b * kPairs + pib;
    float4 c2 = ((const float4*)coords_os)[gp];
    size_t i0 = gp * 2;
    const float* pred_b = pred + (size_t)b * kHW;
    const float* gt_b = gt + (size_t)b * kHW;
    float z0 = sample_bilinear(pred_b, c2.x, c2.y);
    float z1 = sample_bilinear(pred_b, c2.z, c2.w);
    float t0 = sample_bilinear(gt_b, c2.x, c2.y);
    float t1 = sample_bilinear(gt_b, c2.z, c2.w);
    unsigned u0 = __float_as_uint(z0), u1 = __float_as_uint(z1);
    *(uint2*)&pz[i0] = make_uint2(u0, u1);
    *(float2*)&tv[i0] = make_float2(t0, t1);
    unsigned* gh_b = gh + (size_t)b * kBins;
    atomicAdd(&gh_b[(u0 & 0x7fffffffu) >> 17], 1u);
    atomicAdd(&gh_b[(u1 & 0x7fffffffu) >> 17], 1u);
    return;
  }

  if (blk < kSampleBlocks + kBboxBlocks) {
    __shared__ int r0[256], r1[256], r2[256], r3[256];
    int i = blk - kSampleBlocks;
    int x = i & 7;
    int s = i >> 3;                   // 0..31
    int b = x * 2 + (s & 1);
    int c = s >> 1;                   // 0..15
    constexpr int CHUNK4 = kHW / kBXB / 4;  // 4096 float4
    const float4* pred4 = (const float4*)(pred + (size_t)b * kHW) + (size_t)c * CHUNK4;
    int pbase = c * CHUNK4 * 4;
    int xmn = kW, xmx = -1, ymn = kH, ymx = -1;
    for (int i4 = t; i4 < CHUNK4; i4 += 256) {
      float4 z = pred4[i4];
      int p = pbase + i4 * 4;
      int y = p >> 9;
      int x0 = p & (kW - 1);
      if (z.x > 0.0f) { xmn = min(xmn, x0);     xmx = max(xmx, x0);     ymn = min(ymn, y); ymx = max(ymx, y); }
      if (z.y > 0.0f) { xmn = min(xmn, x0 + 1); xmx = max(xmx, x0 + 1); ymn = min(ymn, y); ymx = max(ymx, y); }
      if (z.z > 0.0f) { xmn = min(xmn, x0 + 2); xmx = max(xmx, x0 + 2); ymn = min(ymn, y); ymx = max(ymx, y); }
      if (z.w > 0.0f) { xmn = min(xmn, x0 + 3); xmx = max(xmx, x0 + 3); ymn = min(ymn, y); ymx = max(ymx, y); }
    }
    r0[t] = xmn; r1[t] = xmx; r2[t] = ymn; r3[t] = ymx;
    __syncthreads();
    for (int s2 = 128; s2 > 0; s2 >>= 1) {
      if (t < s2) {
        r0[t] = min(r0[t], r0[t + s2]);
        r1[t] = max(r1[t], r1[t + s2]);
        r2[t] = min(r2[t], r2[t + s2]);
        r3[t] = max(r3[t], r3[t + s2]);
      }
      __syncthreads();
    }
    if (t == 0) {
      int* o = bbp + ((size_t)b * kBXB + c) * 4;
      o[0] = r0[0]; o[1] = r1[0]; o[2] = r2[0]; o[3] = r3[0];
    }
    return;
  }

  // rand-point CE partials
  {
    __shared__ float red[4][256];
    int i = blk - kSampleBlocks - kBboxBlocks;
    int x = i & 7;
    int s = i >> 3;                   // 0..7
    int b = x * 2 + (s & 1);
    int c = s >> 1;                   // 0..3
    const float* pred_b = pred + (size_t)b * kHW;
    const float* gt_b = gt + (size_t)b * kHW;
    float ce_s = 0.0f, p_s = 0.0f, t_s = 0.0f, pt_s = 0.0f;
    for (int e = c * 256 + t; e < kNRAND; e += kRPB * 256) {
      float2 cc = *(const float2*)&coords_rand[((size_t)b * kNRAND + e) * 2];
      float z = sample_bilinear(pred_b, cc.x, cc.y);
      float tt = sample_bilinear(gt_b, cc.x, cc.y);
      float ce, p;
      ce_pair(z, tt, ce, p);
      ce_s += ce; p_s += p; t_s += tt; pt_s += p * tt;
    }
    red[0][t] = ce_s; red[1][t] = p_s; red[2][t] = t_s; red[3][t] = pt_s;
    __syncthreads();
    for (int s2 = 128; s2 > 0; s2 >>= 1) {
      if (t < s2) {
        red[0][t] += red[0][t + s2];
        red[1][t] += red[1][t + s2];
        red[2][t] += red[2][t + s2];
        red[3][t] += red[3][t + s2];
      }
      __syncthreads();
    }
    if (t == 0) {
      float* o = plp + ((size_t)b * kRPB + c) * 4;
      o[0] = red[0][0]; o[1] = red[1][0]; o[2] = red[2][0]; o[3] = red[3][0];
    }
  }
}

// ---- K2: 256 blocks; each does region chunk + hist scan + os-CE slice ----
__global__ __launch_bounds__(1024) void fused2_kernel(const unsigned* __restrict__ pz,
                                                      const float* __restrict__ tv,
                                                      const float* __restrict__ pred,
                                                      const float* __restrict__ gt,
                                                      const unsigned* __restrict__ gh,
                                                      const int* __restrict__ bbp,
                                                      float* __restrict__ osp2,
                                                      float* __restrict__ rgp,
                                                      int* __restrict__ cand,
                                                      int* __restrict__ ccnt,
                                                      int* __restrict__ binfo) {
  __shared__ unsigned sums[1024];
  __shared__ int s_bstar, s_need;
  int blk = blockIdx.x;
  int t = threadIdx.x;
  int x = blk & 7;
  int s = blk >> 3;                 // 0..31
  int b = x * 2 + (s & 1);          // XCD-clustered: batch b on XCD b/2
  int c = s >> 1;                   // 0..15

  // ---- region chunk (HBM stream; issue first) ----
  {
    constexpr int CHUNK4 = kHW / kSLB / 4;  // 4096 float4
    const float4* pred4 = (const float4*)(pred + (size_t)b * kHW) + (size_t)c * CHUNK4;
    const float4* gt4 = (const float4*)(gt + (size_t)b * kHW) + (size_t)c * CHUNK4;
    int xmn = kW, xmx = -1, ymn = kH, ymx = -1;
#pragma unroll
    for (int u = 0; u < kBXB; ++u) {
      const int4 pb = *(const int4*)(bbp + ((size_t)b * kBXB + u) * 4);
      xmn = min(xmn, pb.x); xmx = max(xmx, pb.y);
      ymn = min(ymn, pb.z); ymx = max(ymx, pb.w);
    }
    bool empty = (xmx < 0);
    int x1 = empty ? 0 : xmn;
    int x2 = min(empty ? (kW - 1) : xmx, kW - 1);
    int y1 = empty ? 0 : ymn;
    int y2 = min(empty ? (kH - 1) : ymx, kH - 1);
    bool valid = (x2 > x1) && (y2 > y1);

    int pbase = c * CHUNK4 * 4;
    float wsum = 0.0f, bcew = 0.0f, inter = 0.0f, pw = 0.0f, gw = 0.0f;
    for (int i4 = t; i4 < CHUNK4; i4 += 1024) {
      float4 zv = pred4[i4];
      float4 gv = gt4[i4];
      int p = pbase + i4 * 4;
      int y = p >> 9;
      int x0 = p & (kW - 1);
      bool iny = valid && (y >= y1) && (y <= y2);
#pragma unroll
      for (int l = 0; l < 4; ++l) {
        float z = (l == 0) ? zv.x : (l == 1) ? zv.y : (l == 2) ? zv.z : zv.w;
        float g = (l == 0) ? gv.x : (l == 1) ? gv.y : (l == 2) ? gv.z : gv.w;
        int xx = x0 + l;
        float w = (iny && xx >= x1 && xx <= x2) ? 2.0f : 0.5f;
        float a = expf(-fabsf(z));
        float sp = fmaxf(-z, 0.0f) + log1pf(a);
        float bce = sp + (1.0f - g) * z;
        float inv = 1.0f / (1.0f + a);
        float pp = (z >= 0.0f) ? inv : a * inv;
        wsum += w;
        bcew += bce * w;
        inter += pp * g * w;
        pw += pp * w;
        gw += g * w;
      }
    }
    float* redf = (float*)sums;
    float vals[5] = {wsum, bcew, inter, pw, gw};
#pragma unroll
    for (int q5 = 0; q5 < 5; ++q5) {
      float v = vals[q5];
      for (int o = 32; o > 0; o >>= 1) v += __shfl_down(v, o, 64);
      if ((t & 63) == 0) redf[(t >> 6) * 5 + q5] = v;
    }
    __syncthreads();
    if (t == 0) {
      float o0 = 0, o1 = 0, o2 = 0, o3 = 0, o4 = 0;
      for (int w = 0; w < 16; ++w) {
        o0 += redf[w * 5 + 0]; o1 += redf[w * 5 + 1]; o2 += redf[w * 5 + 2];
        o3 += redf[w * 5 + 3]; o4 += redf[w * 5 + 4];
      }
      float* o = rgp + ((size_t)b * kSLB + c) * 5;
      o[0] = o0; o[1] = o1; o[2] = o2; o[3] = o3; o[4] = o4;
    }
    __syncthreads();
  }

  // ---- boundary search from global hist (r7-verified shfl hierarchy) ----
  {
    const unsigned* h = gh + (size_t)b * kBins;
    unsigned sloc = 0;
#pragma unroll
    for (int k = 0; k < 16; ++k) sloc += h[t * 16 + k];   // bins t*16..t*16+15
    sums[t] = sloc;
    __syncthreads();
    if (t < 64) {
      const unsigned K = (unsigned)kNUNC;
      unsigned v = 0;
#pragma unroll
      for (int k = 0; k < 16; ++k) v += sums[t * 16 + k]; // bins t*256..
      unsigned cum = v;
      for (int off = 1; off < 64; off <<= 1) {
        unsigned xx = __shfl_up(cum, off, 64);
        if (t >= off) cum += xx;
      }
      unsigned long long m = __ballot(cum >= K);
      int L = (int)__ffsll(m) - 1;
      unsigned base1 = __shfl(cum - v, L, 64);
      unsigned v2 = (t < 16) ? sums[L * 16 + t] : 0u;
      unsigned cum2 = v2;
      for (int off = 1; off < 16; off <<= 1) {
        unsigned xx = __shfl_up(cum2, off, 64);
        if (t >= off) cum2 += xx;
      }
      unsigned long long m2 = __ballot((t < 16) && (base1 + cum2 >= K));
      int M = (int)__ffsll(m2) - 1;
      unsigned base2 = __shfl(base1 + cum2 - v2, M, 64);
      int E = L * 16 + M;
      unsigned v3 = (t < 16) ? h[E * 16 + t] : 0u;
      unsigned cum3 = v3;
      for (int off = 1; off < 16; off <<= 1) {
        unsigned xx = __shfl_up(cum3, off, 64);
        if (t >= off) cum3 += xx;
      }
      unsigned long long m3 = __ballot((t < 16) && (base2 + cum3 >= K));
      int F = (int)__ffsll(m3) - 1;
      if (t == F) {
        s_bstar = E * 16 + F;
        s_need = (int)(K - (base2 + cum3 - v3));
      }
    }
    __syncthreads();
  }
  int bstar = s_bstar;
  int need = s_need;
  if (c == 0 && t == 0) { binfo[b * 2] = bstar; binfo[b * 2 + 1] = need; }

  // ---- os-CE slice: points [c*2352, (c+1)*2352), branchless accumulate ----
  {
    float ce_s = 0.0f, p_s = 0.0f, t_s = 0.0f, pt_s = 0.0f;
    if (t < kSlice4) {
      int g4 = b * kNS4 + c * kSlice4 + t;         // global uint4 index
      uint4 u = ((const uint4*)pz)[g4];
      float4 tt4 = ((const float4*)tv)[g4];
      int lbase = (c * kSlice4 + t) * 4;           // local point index in batch
#pragma unroll
      for (int e = 0; e < 4; ++e) {
        unsigned ub = (e == 0) ? u.x : (e == 1) ? u.y : (e == 2) ? u.z : u.w;
        float ttv = (e == 0) ? tt4.x : (e == 1) ? tt4.y : (e == 2) ? tt4.z : tt4.w;
        int bin = (int)((ub & 0x7fffffffu) >> 17);
        float z = __uint_as_float(ub);
        float ce, p;
        ce_pair(z, ttv, ce, p);
        float w = (bin < bstar) ? 1.0f : 0.0f;
        ce_s += w * ce; p_s += w * p; t_s += w * ttv; pt_s += w * p * ttv;
        if (bin == bstar) {
          int pos = atomicAdd(&ccnt[b], 1);
          if (pos < kCAP) cand[b * kCAP + pos] = lbase + e;
        }
      }
    }
    float* redf = (float*)sums;
    float vals[4] = {ce_s, p_s, t_s, pt_s};
#pragma unroll
    for (int q = 0; q < 4; ++q) {
      float v = vals[q];
      for (int o = 32; o > 0; o >>= 1) v += __shfl_down(v, o, 64);
      if ((t & 63) == 0) redf[(t >> 6) * 4 + q] = v;
    }
    __syncthreads();
    if (t == 0) {
      float o0 = 0, o1 = 0, o2 = 0, o3 = 0;
      for (int w = 0; w < 16; ++w) {
        o0 += redf[w * 4 + 0]; o1 += redf[w * 4 + 1];
        o2 += redf[w * 4 + 2]; o3 += redf[w * 4 + 3];
      }
      float* o = osp2 + ((size_t)b * kSLB + c) * 4;
      o[0] = o0; o[1] = o1; o[2] = o2; o[3] = o3;
    }
  }
}

// ---- K3: 16 blocks (one per batch, XCD-clustered): boundary rank + CE partial ----
__global__ __launch_bounds__(1024) void rank_kernel(const unsigned* __restrict__ pz,
                                                    const float* __restrict__ tv,
                                                    const int* __restrict__ cand,
                                                    const int* __restrict__ ccnt,
                                                    const int* __restrict__ binfo,
                                                    float* __restrict__ bsum) {
  __shared__ int scand[kCAP];
  __shared__ int ssort[kCAP];
  __shared__ unsigned usums[1024];
  __shared__ float redf[16 * 4];
  __shared__ int s_round;
  int t = threadIdx.x;
  int blk = blockIdx.x;
  int b = (blk & 7) * 2 + (blk >> 3);   // batch b on XCD b/2 (matches K1/K2 residue)

  int bstar = binfo[b * 2];
  int need = binfo[b * 2 + 1];
  int c = ccnt[b];
  const unsigned* pz_b = pz + (size_t)b * kNS;
  const float* tv_b = tv + (size_t)b * kNS;
  float ce_s = 0.0f, p_s = 0.0f, t_s = 0.0f, pt_s = 0.0f;

  if (c <= kCAP) {
    for (int i = t; i < c; i += 1024) scand[i] = cand[b * kCAP + i];
    __syncthreads();
    for (int i = t; i < c; i += 1024) {
      int my = scand[i];
      int r = 0;
      for (int k = 0; k < c; ++k) r += (scand[k] < my) ? 1 : 0;
      ssort[r] = my;
    }
    __syncthreads();
    for (int r = t; r < need; r += 1024) {
      int my = ssort[r];
      float z = __uint_as_float(pz_b[my]);
      float ttv = tv_b[my];
      float ce, p;
      ce_pair(z, ttv, ce, p);
      ce_s += ce; p_s += p; t_s += ttv; pt_s += p * ttv;
    }
  } else {
    // ordered-scan fallback over full batch (duplicate-heavy pathological data)
    if (t == 0) s_round = 0;
    __syncthreads();
    for (int j = 0; j < 10; ++j) {
      int idx4 = j * 1024 + t;
      unsigned meq = 0u;
      if (idx4 < kNS4) {
        uint4 u = ((const uint4*)pz_b)[idx4];
        meq = (unsigned)((int)((u.x & 0x7fffffffu) >> 17) == bstar) |
              ((unsigned)((int)((u.y & 0x7fffffffu) >> 17) == bstar) << 1) |
              ((unsigned)((int)((u.z & 0x7fffffffu) >> 17) == bstar) << 2) |
              ((unsigned)((int)((u.w & 0x7fffffffu) >> 17) == bstar) << 3);
      }
      unsigned cnt2 = __popc(meq);
      usums[t] = cnt2;
      __syncthreads();
      for (int off = 1; off < 1024; off <<= 1) {
        unsigned v = (t >= off) ? usums[t - off] : 0u;
        __syncthreads();
        usums[t] += v;
        __syncthreads();
      }
      int myBase = s_round + (int)(usums[t] - cnt2);
      unsigned mm = meq;
      while (mm) {
        int e = __ffs(mm) - 1;
        mm &= mm - 1;
        if (myBase < need) {
          int my = idx4 * 4 + e;
          float z = __uint_as_float(pz_b[my]);
          float ttv = tv_b[my];
          float ce, p;
          ce_pair(z, ttv, ce, p);
          ce_s += ce; p_s += p; t_s += ttv; pt_s += p * ttv;
        }
        myBase++;
      }
      __syncthreads();
      if (t == 0) s_round += (int)usums[1023];
      __syncthreads();
    }
  }

  float vals[4] = {ce_s, p_s, t_s, pt_s};
#pragma unroll
  for (int q = 0; q < 4; ++q) {
    float v = vals[q];
    for (int o = 32; o > 0; o >>= 1) v += __shfl_down(v, o, 64);
    if ((t & 63) == 0) redf[(t >> 6) * 4 + q] = v;
  }
  __syncthreads();
  if (t == 0) {
    float o0 = 0, o1 = 0, o2 = 0, o3 = 0;
    for (int w = 0; w < 16; ++w) {
      o0 += redf[w * 4 + 0]; o1 += redf[w * 4 + 1];
      o2 += redf[w * 4 + 2]; o3 += redf[w * 4 + 3];
    }
    float* o = bsum + (size_t)b * 4;
    o[0] = o0; o[1] = o1; o[2] = o2; o[3] = o3;
  }
}

// ---- K4: f64 finalize (1 block, 64 threads) ----
__global__ __launch_bounds__(64) void finalize_kernel(const float* __restrict__ bsum,
                                                      const float* __restrict__ osp2,
                                                      const float* __restrict__ plp,
                                                      const float* __restrict__ rgp,
                                                      float* __restrict__ out) {
  __shared__ double shd[kB][4];
  int t = threadIdx.x;
  if (t < kB) {
    const float* o = bsum + (size_t)t * 4;
    double ce = o[0], p = o[1], tt = o[2], pt = o[3];
    for (int c = 0; c < kSLB; ++c) {
      const float* q = osp2 + ((size_t)t * kSLB + c) * 4;
      ce += q[0]; p += q[1]; tt += q[2]; pt += q[3];
    }
    for (int c = 0; c < kRPB; ++c) {
      const float* q = plp + ((size_t)t * kRPB + c) * 4;
      ce += q[0]; p += q[1]; tt += q[2]; pt += q[3];
    }
    double ws = 0, bc = 0, in = 0, pw = 0, gw = 0;
    for (int c = 0; c < kSLB; ++c) {
      const float* q = rgp + ((size_t)t * kSLB + c) * 5;
      ws += q[0]; bc += q[1]; in += q[2]; pw += q[3]; gw += q[4];
    }
    shd[t][0] = ce / (double)kNPTS;
    shd[t][1] = 1.0 - (2.0 * pt + 1.0) / (p + tt + 1.0);
    double wss = ws > 1e-6 ? ws : 1e-6;
    shd[t][2] = bc / wss;
    shd[t][3] = 1.0 - (2.0 * in + 1.0) / (pw + gw + 1.0);
  }
  __syncthreads();
  if (t == 0) {
    double a = 0, b2 = 0, c2 = 0, d = 0;
    for (int i = 0; i < kB; ++i) { a += shd[i][0]; b2 += shd[i][1]; c2 += shd[i][2]; d += shd[i][3]; }
    out[0] = (float)(a / 16.0);
    out[1] = (float)(b2 / 16.0);
    out[2] = (float)(c2 / 16.0);
    out[3] = (float)(d / 16.0);
  }
}

extern "C" void kernel_launch(void* const* d_in, const int* in_sizes, int n_in,
                              void* d_out, int out_size, void* d_ws, size_t ws_size,
                              hipStream_t stream) {
  const float* pred = (const float*)d_in[0];
  const float* gt = (const float*)d_in[1];
  const float* coords_os = (const float*)d_in[2];
  const float* coords_rand = (const float*)d_in[3];
  float* out = (float*)d_out;
  char* ws = (char*)d_ws;

  unsigned* pz = (unsigned*)(ws + OFF_PZ);
  float* tv = (float*)(ws + OFF_TV);
  unsigned* gh = (unsigned*)(ws + OFF_GH);
  int* bbp = (int*)(ws + OFF_BBP);
  float* plp = (float*)(ws + OFF_PLP);
  float* osp2 = (float*)(ws + OFF_OSP2);
  float* rgp = (float*)(ws + OFF_RGP);
  int* cand = (int*)(ws + OFF_CAND);
  int* ccnt = (int*)(ws + OFF_CCNT);
  int* binfo = (int*)(ws + OFF_BNFO);
  float* bsum = (float*)(ws + OFF_BSUM);

  zero_kernel<<<(kB * kBins + 1023) / 1024, 1024, 0, stream>>>(gh, ccnt);
  fused1_kernel<<<kSampleBlocks + kBboxBlocks + kRandBlocks, 256, 0, stream>>>(
      pred, gt, coords_os, coords_rand, pz, tv, gh, bbp, plp);
  fused2_kernel<<<kB * kSLB, 1024, 0, stream>>>(pz, tv, pred, gt, gh, bbp,
                                                osp2, rgp, cand, ccnt, binfo);
  rank_kernel<<<kB, 1024, 0, stream>>>(pz, tv, cand, ccnt, binfo, bsum);
  finalize_kernel<<<1, 64, 0, stream>>>(bsum, osp2, plp, rgp, out);
}

// Round 13
// 83.515 us; speedup vs baseline: 2.1821x; 1.3398x over previous
//
#include <hip/hip_runtime.h>
#include <cstdint>
#include <cstddef>

namespace {

constexpr int kB = 16;
constexpr int kH = 512;
constexpr int kW = 512;
constexpr int kHW = kH * kW;
constexpr int kNS = 37632;     // NUM_POINTS * OVERSAMPLE
constexpr int kNS4 = kNS / 4;  // 9408
constexpr int kNUNC = 9408;
constexpr int kNRAND = 3136;
constexpr int kNPTS = 12544;
constexpr int kBXB = 16;       // bbox partial blocks per batch
constexpr int kRPB = 4;        // rand-point blocks per batch
constexpr int kSLB = 16;       // slices per batch in K2 (os-CE + region)
constexpr int kSlice4 = kNS4 / kSLB;    // 588
constexpr int kPairs = kNS / 2;
constexpr int kSampSlots = 148;
constexpr int kSampleBlocks = 8 * kSampSlots;    // 1184
constexpr int kBboxBlocks = kB * kBXB;           // 256
constexpr int kRandBlocks = kB * kRPB;           // 64
constexpr int kHStride = 1025;                   // swizzled hist row stride (words)
constexpr int kCAP = 2048;

// workspace layout (bytes)
constexpr size_t OFF_PZ   = 0;                                     // [B][NS] u32 signed z bits
constexpr size_t OFF_TV   = OFF_PZ + (size_t)kB * kNS * 4;         // [B][NS] f32 gt label
constexpr size_t OFF_BBP  = OFF_TV + (size_t)kB * kNS * 4;         // [B][16][4] i32
constexpr size_t OFF_PLP  = OFF_BBP + (size_t)kB * kBXB * 4 * 4;   // [B][4][4] f32 rand partials
constexpr size_t OFF_OSP2 = OFF_PLP + (size_t)kB * kRPB * 4 * 4;   // [B][16][4] f32 os slice sums
constexpr size_t OFF_RGP  = OFF_OSP2 + (size_t)kB * kSLB * 4 * 4;  // [B][16][5] f32 region partials
constexpr size_t OFF_CAND = OFF_RGP + (size_t)kB * kSLB * 5 * 4;   // [B][2048] i32
constexpr size_t OFF_CCNT = OFF_CAND + (size_t)kB * kCAP * 4;      // [B] i32 (pad 64)
constexpr size_t OFF_BNFO = OFF_CCNT + 256;                        // [B][2] i32 (bstar, need)
constexpr size_t OFF_BSUM = OFF_BNFO + 256;                        // [B][4] f32 boundary sums

// Swizzled hist: bin -> (bin&15)*1025 + (bin>>4). Row sums hist[k*1025+t] are
// lane-stride-1 (conflict-free); 1025%32==1 keeps adjacent bins in distinct banks.
__device__ __forceinline__ int SW(int bin) {
  return (bin & 15) * kHStride + (bin >> 4);
}

} // namespace

__device__ __forceinline__ float sample_bilinear(const float* __restrict__ img,
                                                 float cx, float cy) {
  float x = cx * (float)kW - 0.5f;
  float y = cy * (float)kH - 0.5f;
  float x0f = floorf(x), y0f = floorf(y);
  float wx1 = x - x0f, wx0 = 1.0f - wx1;
  float wy1 = y - y0f, wy0 = 1.0f - wy1;
  int x0 = (int)x0f, y0 = (int)y0f;
  int x1 = x0 + 1, y1 = y0 + 1;
  int xc0 = min(max(x0, 0), kW - 1), xc1 = min(max(x1, 0), kW - 1);
  int yc0 = min(max(y0, 0), kH - 1), yc1 = min(max(y1, 0), kH - 1);
  float v00 = ((x0 >= 0) && (x0 < kW) && (y0 >= 0) && (y0 < kH)) ? img[yc0 * kW + xc0] : 0.0f;
  float v01 = ((x1 >= 0) && (x1 < kW) && (y0 >= 0) && (y0 < kH)) ? img[yc0 * kW + xc1] : 0.0f;
  float v10 = ((x0 >= 0) && (x0 < kW) && (y1 >= 0) && (y1 < kH)) ? img[yc1 * kW + xc0] : 0.0f;
  float v11 = ((x1 >= 0) && (x1 < kW) && (y1 >= 0) && (y1 < kH)) ? img[yc1 * kW + xc1] : 0.0f;
  return v00 * (wy0 * wx0) + v01 * (wy0 * wx1) + v10 * (wy1 * wx0) + v11 * (wy1 * wx1);
}

__device__ __forceinline__ void ce_pair(float z, float tt, float& ce, float& p) {
  float a = expf(-fabsf(z));
  ce = fmaxf(z, 0.0f) - z * tt + log1pf(a);
  float inv = 1.0f / (1.0f + a);
  p = (z >= 0.0f) ? inv : a * inv;
}

// ---- K1: os sampling (pz/tv stores only, NO atomics) | bbox | rand CE ----
__global__ __launch_bounds__(256) void fused1_kernel(const float* __restrict__ pred,
                                                     const float* __restrict__ gt,
                                                     const float* __restrict__ coords_os,
                                                     const float* __restrict__ coords_rand,
                                                     unsigned* __restrict__ pz,
                                                     float* __restrict__ tv,
                                                     int* __restrict__ bbp,
                                                     float* __restrict__ plp,
                                                     int* __restrict__ ccnt) {
  int blk = blockIdx.x;
  int t = threadIdx.x;

  if (blk == 0 && t < kB) ccnt[t] = 0;   // reset candidate counters every call

  if (blk < kSampleBlocks) {
    int x = blk & 7;
    int s = blk >> 3;                 // 0..147
    int b = x * 2 + (s & 1);          // XCD-clustered: batch b on XCD b/2
    int chunk = s >> 1;               // 0..73
    int pib = chunk * 256 + t;
    if (pib >= kPairs) return;
    size_t gp = (size_t)b * kPairs + pib;
    float4 c2 = ((const float4*)coords_os)[gp];
    size_t i0 = gp * 2;
    const float* pred_b = pred + (size_t)b * kHW;
    const float* gt_b = gt + (size_t)b * kHW;
    float z0 = sample_bilinear(pred_b, c2.x, c2.y);
    float z1 = sample_bilinear(pred_b, c2.z, c2.w);
    float t0 = sample_bilinear(gt_b, c2.x, c2.y);
    float t1 = sample_bilinear(gt_b, c2.z, c2.w);
    *(uint2*)&pz[i0] = make_uint2(__float_as_uint(z0), __float_as_uint(z1));
    *(float2*)&tv[i0] = make_float2(t0, t1);
    return;
  }

  if (blk < kSampleBlocks + kBboxBlocks) {
    __shared__ int r0[256], r1[256], r2[256], r3[256];
    int i = blk - kSampleBlocks;
    int x = i & 7;
    int s = i >> 3;                   // 0..31
    int b = x * 2 + (s & 1);
    int c = s >> 1;                   // 0..15
    constexpr int CHUNK4 = kHW / kBXB / 4;  // 4096 float4
    const float4* pred4 = (const float4*)(pred + (size_t)b * kHW) + (size_t)c * CHUNK4;
    int pbase = c * CHUNK4 * 4;
    int xmn = kW, xmx = -1, ymn = kH, ymx = -1;
    for (int i4 = t; i4 < CHUNK4; i4 += 256) {
      float4 z = pred4[i4];
      int p = pbase + i4 * 4;
      int y = p >> 9;
      int x0 = p & (kW - 1);
      if (z.x > 0.0f) { xmn = min(xmn, x0);     xmx = max(xmx, x0);     ymn = min(ymn, y); ymx = max(ymx, y); }
      if (z.y > 0.0f) { xmn = min(xmn, x0 + 1); xmx = max(xmx, x0 + 1); ymn = min(ymn, y); ymx = max(ymx, y); }
      if (z.z > 0.0f) { xmn = min(xmn, x0 + 2); xmx = max(xmx, x0 + 2); ymn = min(ymn, y); ymx = max(ymx, y); }
      if (z.w > 0.0f) { xmn = min(xmn, x0 + 3); xmx = max(xmx, x0 + 3); ymn = min(ymn, y); ymx = max(ymx, y); }
    }
    r0[t] = xmn; r1[t] = xmx; r2[t] = ymn; r3[t] = ymx;
    __syncthreads();
    for (int s2 = 128; s2 > 0; s2 >>= 1) {
      if (t < s2) {
        r0[t] = min(r0[t], r0[t + s2]);
        r1[t] = max(r1[t], r1[t + s2]);
        r2[t] = min(r2[t], r2[t + s2]);
        r3[t] = max(r3[t], r3[t + s2]);
      }
      __syncthreads();
    }
    if (t == 0) {
      int* o = bbp + ((size_t)b * kBXB + c) * 4;
      o[0] = r0[0]; o[1] = r1[0]; o[2] = r2[0]; o[3] = r3[0];
    }
    return;
  }

  // rand-point CE partials
  {
    __shared__ float red[4][256];
    int i = blk - kSampleBlocks - kBboxBlocks;
    int x = i & 7;
    int s = i >> 3;                   // 0..7
    int b = x * 2 + (s & 1);
    int c = s >> 1;                   // 0..3
    const float* pred_b = pred + (size_t)b * kHW;
    const float* gt_b = gt + (size_t)b * kHW;
    float ce_s = 0.0f, p_s = 0.0f, t_s = 0.0f, pt_s = 0.0f;
    for (int e = c * 256 + t; e < kNRAND; e += kRPB * 256) {
      float2 cc = *(const float2*)&coords_rand[((size_t)b * kNRAND + e) * 2];
      float z = sample_bilinear(pred_b, cc.x, cc.y);
      float tt = sample_bilinear(gt_b, cc.x, cc.y);
      float ce, p;
      ce_pair(z, tt, ce, p);
      ce_s += ce; p_s += p; t_s += tt; pt_s += p * tt;
    }
    red[0][t] = ce_s; red[1][t] = p_s; red[2][t] = t_s; red[3][t] = pt_s;
    __syncthreads();
    for (int s2 = 128; s2 > 0; s2 >>= 1) {
      if (t < s2) {
        red[0][t] += red[0][t + s2];
        red[1][t] += red[1][t + s2];
        red[2][t] += red[2][t + s2];
        red[3][t] += red[3][t + s2];
      }
      __syncthreads();
    }
    if (t == 0) {
      float* o = plp + ((size_t)b * kRPB + c) * 4;
      o[0] = red[0][0]; o[1] = red[1][0]; o[2] = red[2][0]; o[3] = red[3][0];
    }
  }
}

// ---- K2: 256 blocks; region chunk + per-block LDS hist (full batch) + os-CE slice ----
__global__ __launch_bounds__(1024) void fused2_kernel(const unsigned* __restrict__ pz,
                                                      const float* __restrict__ tv,
                                                      const float* __restrict__ pred,
                                                      const float* __restrict__ gt,
                                                      const int* __restrict__ bbp,
                                                      float* __restrict__ osp2,
                                                      float* __restrict__ rgp,
                                                      int* __restrict__ cand,
                                                      int* __restrict__ ccnt,
                                                      int* __restrict__ binfo) {
  __shared__ unsigned hist[16 * kHStride];   // 65.6 KB swizzled
  __shared__ unsigned sums[1024];
  __shared__ int s_bstar, s_need;
  int blk = blockIdx.x;
  int t = threadIdx.x;
  int x = blk & 7;
  int s = blk >> 3;                 // 0..31
  int b = x * 2 + (s & 1);          // XCD-clustered: batch b on XCD b/2
  int c = s >> 1;                   // 0..15
  const uint4* pz4_b = (const uint4*)(pz + (size_t)b * kNS);

  // ---- region chunk (HBM stream) ----
  {
    constexpr int CHUNK4 = kHW / kSLB / 4;  // 4096 float4
    const float4* pred4 = (const float4*)(pred + (size_t)b * kHW) + (size_t)c * CHUNK4;
    const float4* gt4 = (const float4*)(gt + (size_t)b * kHW) + (size_t)c * CHUNK4;
    int xmn = kW, xmx = -1, ymn = kH, ymx = -1;
#pragma unroll
    for (int u = 0; u < kBXB; ++u) {
      const int4 pb = *(const int4*)(bbp + ((size_t)b * kBXB + u) * 4);
      xmn = min(xmn, pb.x); xmx = max(xmx, pb.y);
      ymn = min(ymn, pb.z); ymx = max(ymx, pb.w);
    }
    bool empty = (xmx < 0);
    int x1 = empty ? 0 : xmn;
    int x2 = min(empty ? (kW - 1) : xmx, kW - 1);
    int y1 = empty ? 0 : ymn;
    int y2 = min(empty ? (kH - 1) : ymx, kH - 1);
    bool valid = (x2 > x1) && (y2 > y1);

    int pbase = c * CHUNK4 * 4;
    float wsum = 0.0f, bcew = 0.0f, inter = 0.0f, pw = 0.0f, gw = 0.0f;
    for (int i4 = t; i4 < CHUNK4; i4 += 1024) {
      float4 zv = pred4[i4];
      float4 gv = gt4[i4];
      int p = pbase + i4 * 4;
      int y = p >> 9;
      int x0 = p & (kW - 1);
      bool iny = valid && (y >= y1) && (y <= y2);
#pragma unroll
      for (int l = 0; l < 4; ++l) {
        float z = (l == 0) ? zv.x : (l == 1) ? zv.y : (l == 2) ? zv.z : zv.w;
        float g = (l == 0) ? gv.x : (l == 1) ? gv.y : (l == 2) ? gv.z : gv.w;
        int xx = x0 + l;
        float w = (iny && xx >= x1 && xx <= x2) ? 2.0f : 0.5f;
        float a = expf(-fabsf(z));
        float sp = fmaxf(-z, 0.0f) + log1pf(a);
        float bce = sp + (1.0f - g) * z;
        float inv = 1.0f / (1.0f + a);
        float pp = (z >= 0.0f) ? inv : a * inv;
        wsum += w;
        bcew += bce * w;
        inter += pp * g * w;
        pw += pp * w;
        gw += g * w;
      }
    }
    float* redf = (float*)sums;
    float vals[5] = {wsum, bcew, inter, pw, gw};
#pragma unroll
    for (int q5 = 0; q5 < 5; ++q5) {
      float v = vals[q5];
      for (int o = 32; o > 0; o >>= 1) v += __shfl_down(v, o, 64);
      if ((t & 63) == 0) redf[(t >> 6) * 5 + q5] = v;
    }
    __syncthreads();
    if (t == 0) {
      float o0 = 0, o1 = 0, o2 = 0, o3 = 0, o4 = 0;
      for (int w = 0; w < 16; ++w) {
        o0 += redf[w * 5 + 0]; o1 += redf[w * 5 + 1]; o2 += redf[w * 5 + 2];
        o3 += redf[w * 5 + 3]; o4 += redf[w * 5 + 4];
      }
      float* o = rgp + ((size_t)b * kSLB + c) * 5;
      o[0] = o0; o[1] = o1; o[2] = o2; o[3] = o3; o[4] = o4;
    }
    __syncthreads();
  }

  // ---- per-block full-batch LDS histogram (coalesced L2-hot reads, no globals) ----
  {
    for (int i = t; i < 16 * kHStride; i += 1024) hist[i] = 0u;
    __syncthreads();
#pragma unroll 2
    for (int j = 0; j < 10; ++j) {
      int idx4 = j * 1024 + t;
      if (idx4 < kNS4) {
        uint4 u = pz4_b[idx4];
        atomicAdd(&hist[SW((int)((u.x & 0x7fffffffu) >> 17))], 1u);
        atomicAdd(&hist[SW((int)((u.y & 0x7fffffffu) >> 17))], 1u);
        atomicAdd(&hist[SW((int)((u.z & 0x7fffffffu) >> 17))], 1u);
        atomicAdd(&hist[SW((int)((u.w & 0x7fffffffu) >> 17))], 1u);
      }
    }
    __syncthreads();

    // boundary search (r7/r8-verified shfl hierarchy on swizzled layout)
    unsigned sloc = 0;
#pragma unroll
    for (int k = 0; k < 16; ++k) sloc += hist[k * kHStride + t];  // bins t*16..t*16+15
    sums[t] = sloc;
    __syncthreads();
    if (t < 64) {
      const unsigned K = (unsigned)kNUNC;
      unsigned v = 0;
#pragma unroll
      for (int k = 0; k < 16; ++k) v += sums[t * 16 + k];         // bins t*256..
      unsigned cum = v;
      for (int off = 1; off < 64; off <<= 1) {
        unsigned xx = __shfl_up(cum, off, 64);
        if (t >= off) cum += xx;
      }
      unsigned long long m = __ballot(cum >= K);
      int L = (int)__ffsll(m) - 1;
      unsigned base1 = __shfl(cum - v, L, 64);
      unsigned v2 = (t < 16) ? sums[L * 16 + t] : 0u;
      unsigned cum2 = v2;
      for (int off = 1; off < 16; off <<= 1) {
        unsigned xx = __shfl_up(cum2, off, 64);
        if (t >= off) cum2 += xx;
      }
      unsigned long long m2 = __ballot((t < 16) && (base1 + cum2 >= K));
      int M = (int)__ffsll(m2) - 1;
      unsigned base2 = __shfl(base1 + cum2 - v2, M, 64);
      int E = L * 16 + M;
      unsigned v3 = (t < 16) ? hist[t * kHStride + E] : 0u;       // bin E*16+t
      unsigned cum3 = v3;
      for (int off = 1; off < 16; off <<= 1) {
        unsigned xx = __shfl_up(cum3, off, 64);
        if (t >= off) cum3 += xx;
      }
      unsigned long long m3 = __ballot((t < 16) && (base2 + cum3 >= K));
      int F = (int)__ffsll(m3) - 1;
      if (t == F) {
        s_bstar = E * 16 + F;
        s_need = (int)(K - (base2 + cum3 - v3));
      }
    }
    __syncthreads();
  }
  int bstar = s_bstar;
  int need = s_need;
  if (c == 0 && t == 0) { binfo[b * 2] = bstar; binfo[b * 2 + 1] = need; }

  // ---- os-CE slice: points [c*2352, (c+1)*2352), branchless accumulate ----
  {
    float ce_s = 0.0f, p_s = 0.0f, t_s = 0.0f, pt_s = 0.0f;
    if (t < kSlice4) {
      int l4 = c * kSlice4 + t;                    // uint4 index within batch
      uint4 u = pz4_b[l4];
      float4 tt4 = ((const float4*)(tv + (size_t)b * kNS))[l4];
      int lbase = l4 * 4;
#pragma unroll
      for (int e = 0; e < 4; ++e) {
        unsigned ub = (e == 0) ? u.x : (e == 1) ? u.y : (e == 2) ? u.z : u.w;
        float ttv = (e == 0) ? tt4.x : (e == 1) ? tt4.y : (e == 2) ? tt4.z : tt4.w;
        int bin = (int)((ub & 0x7fffffffu) >> 17);
        float z = __uint_as_float(ub);
        float ce, p;
        ce_pair(z, ttv, ce, p);
        float w = (bin < bstar) ? 1.0f : 0.0f;
        ce_s += w * ce; p_s += w * p; t_s += w * ttv; pt_s += w * p * ttv;
        if (bin == bstar) {
          int pos = atomicAdd(&ccnt[b], 1);
          if (pos < kCAP) cand[b * kCAP + pos] = lbase + e;
        }
      }
    }
    float* redf = (float*)sums;
    float vals[4] = {ce_s, p_s, t_s, pt_s};
#pragma unroll
    for (int q = 0; q < 4; ++q) {
      float v = vals[q];
      for (int o = 32; o > 0; o >>= 1) v += __shfl_down(v, o, 64);
      if ((t & 63) == 0) redf[(t >> 6) * 4 + q] = v;
    }
    __syncthreads();
    if (t == 0) {
      float o0 = 0, o1 = 0, o2 = 0, o3 = 0;
      for (int w = 0; w < 16; ++w) {
        o0 += redf[w * 4 + 0]; o1 += redf[w * 4 + 1];
        o2 += redf[w * 4 + 2]; o3 += redf[w * 4 + 3];
      }
      float* o = osp2 + ((size_t)b * kSLB + c) * 4;
      o[0] = o0; o[1] = o1; o[2] = o2; o[3] = o3;
    }
  }
}

// ---- K3: 16 blocks (one per batch, XCD-clustered): boundary rank + CE partial ----
__global__ __launch_bounds__(1024) void rank_kernel(const unsigned* __restrict__ pz,
                                                    const float* __restrict__ tv,
                                                    const int* __restrict__ cand,
                                                    const int* __restrict__ ccnt,
                                                    const int* __restrict__ binfo,
                                                    float* __restrict__ bsum) {
  __shared__ int scand[kCAP];
  __shared__ int ssort[kCAP];
  __shared__ unsigned usums[1024];
  __shared__ float redf[16 * 4];
  __shared__ int s_round;
  int t = threadIdx.x;
  int blk = blockIdx.x;
  int b = (blk & 7) * 2 + (blk >> 3);   // batch b on XCD b/2 (matches K1/K2 residue)

  int bstar = binfo[b * 2];
  int need = binfo[b * 2 + 1];
  int c = ccnt[b];
  const unsigned* pz_b = pz + (size_t)b * kNS;
  const float* tv_b = tv + (size_t)b * kNS;
  float ce_s = 0.0f, p_s = 0.0f, t_s = 0.0f, pt_s = 0.0f;

  if (c <= kCAP) {
    for (int i = t; i < c; i += 1024) scand[i] = cand[b * kCAP + i];
    __syncthreads();
    for (int i = t; i < c; i += 1024) {
      int my = scand[i];
      int r = 0;
      for (int k = 0; k < c; ++k) r += (scand[k] < my) ? 1 : 0;
      ssort[r] = my;
    }
    __syncthreads();
    for (int r = t; r < need; r += 1024) {
      int my = ssort[r];
      float z = __uint_as_float(pz_b[my]);
      float ttv = tv_b[my];
      float ce, p;
      ce_pair(z, ttv, ce, p);
      ce_s += ce; p_s += p; t_s += ttv; pt_s += p * ttv;
    }
  } else {
    // ordered-scan fallback over full batch (duplicate-heavy pathological data)
    if (t == 0) s_round = 0;
    __syncthreads();
    for (int j = 0; j < 10; ++j) {
      int idx4 = j * 1024 + t;
      unsigned meq = 0u;
      if (idx4 < kNS4) {
        uint4 u = ((const uint4*)pz_b)[idx4];
        meq = (unsigned)((int)((u.x & 0x7fffffffu) >> 17) == bstar) |
              ((unsigned)((int)((u.y & 0x7fffffffu) >> 17) == bstar) << 1) |
              ((unsigned)((int)((u.z & 0x7fffffffu) >> 17) == bstar) << 2) |
              ((unsigned)((int)((u.w & 0x7fffffffu) >> 17) == bstar) << 3);
      }
      unsigned cnt2 = __popc(meq);
      usums[t] = cnt2;
      __syncthreads();
      for (int off = 1; off < 1024; off <<= 1) {
        unsigned v = (t >= off) ? usums[t - off] : 0u;
        __syncthreads();
        usums[t] += v;
        __syncthreads();
      }
      int myBase = s_round + (int)(usums[t] - cnt2);
      unsigned mm = meq;
      while (mm) {
        int e = __ffs(mm) - 1;
        mm &= mm - 1;
        if (myBase < need) {
          int my = idx4 * 4 + e;
          float z = __uint_as_float(pz_b[my]);
          float ttv = tv_b[my];
          float ce, p;
          ce_pair(z, ttv, ce, p);
          ce_s += ce; p_s += p; t_s += ttv; pt_s += p * ttv;
        }
        myBase++;
      }
      __syncthreads();
      if (t == 0) s_round += (int)usums[1023];
      __syncthreads();
    }
  }

  float vals[4] = {ce_s, p_s, t_s, pt_s};
#pragma unroll
  for (int q = 0; q < 4; ++q) {
    float v = vals[q];
    for (int o = 32; o > 0; o >>= 1) v += __shfl_down(v, o, 64);
    if ((t & 63) == 0) redf[(t >> 6) * 4 + q] = v;
  }
  __syncthreads();
  if (t == 0) {
    float o0 = 0, o1 = 0, o2 = 0, o3 = 0;
    for (int w = 0; w < 16; ++w) {
      o0 += redf[w * 4 + 0]; o1 += redf[w * 4 + 1];
      o2 += redf[w * 4 + 2]; o3 += redf[w * 4 + 3];
    }
    float* o = bsum + (size_t)b * 4;
    o[0] = o0; o[1] = o1; o[2] = o2; o[3] = o3;
  }
}

// ---- K4: f64 finalize (1 block, 64 threads) ----
__global__ __launch_bounds__(64) void finalize_kernel(const float* __restrict__ bsum,
                                                      const float* __restrict__ osp2,
                                                      const float* __restrict__ plp,
                                                      const float* __restrict__ rgp,
                                                      float* __restrict__ out) {
  __shared__ double shd[kB][4];
  int t = threadIdx.x;
  if (t < kB) {
    const float* o = bsum + (size_t)t * 4;
    double ce = o[0], p = o[1], tt = o[2], pt = o[3];
    for (int c = 0; c < kSLB; ++c) {
      const float* q = osp2 + ((size_t)t * kSLB + c) * 4;
      ce += q[0]; p += q[1]; tt += q[2]; pt += q[3];
    }
    for (int c = 0; c < kRPB; ++c) {
      const float* q = plp + ((size_t)t * kRPB + c) * 4;
      ce += q[0]; p += q[1]; tt += q[2]; pt += q[3];
    }
    double ws = 0, bc = 0, in = 0, pw = 0, gw = 0;
    for (int c = 0; c < kSLB; ++c) {
      const float* q = rgp + ((size_t)t * kSLB + c) * 5;
      ws += q[0]; bc += q[1]; in += q[2]; pw += q[3]; gw += q[4];
    }
    shd[t][0] = ce / (double)kNPTS;
    shd[t][1] = 1.0 - (2.0 * pt + 1.0) / (p + tt + 1.0);
    double wss = ws > 1e-6 ? ws : 1e-6;
    shd[t][2] = bc / wss;
    shd[t][3] = 1.0 - (2.0 * in + 1.0) / (pw + gw + 1.0);
  }
  __syncthreads();
  if (t == 0) {
    double a = 0, b2 = 0, c2 = 0, d = 0;
    for (int i = 0; i < kB; ++i) { a += shd[i][0]; b2 += shd[i][1]; c2 += shd[i][2]; d += shd[i][3]; }
    out[0] = (float)(a / 16.0);
    out[1] = (float)(b2 / 16.0);
    out[2] = (float)(c2 / 16.0);
    out[3] = (float)(d / 16.0);
  }
}

extern "C" void kernel_launch(void* const* d_in, const int* in_sizes, int n_in,
                              void* d_out, int out_size, void* d_ws, size_t ws_size,
                              hipStream_t stream) {
  const float* pred = (const float*)d_in[0];
  const float* gt = (const float*)d_in[1];
  const float* coords_os = (const float*)d_in[2];
  const float* coords_rand = (const float*)d_in[3];
  float* out = (float*)d_out;
  char* ws = (char*)d_ws;

  unsigned* pz = (unsigned*)(ws + OFF_PZ);
  float* tv = (float*)(ws + OFF_TV);
  int* bbp = (int*)(ws + OFF_BBP);
  float* plp = (float*)(ws + OFF_PLP);
  float* osp2 = (float*)(ws + OFF_OSP2);
  float* rgp = (float*)(ws + OFF_RGP);
  int* cand = (int*)(ws + OFF_CAND);
  int* ccnt = (int*)(ws + OFF_CCNT);
  int* binfo = (int*)(ws + OFF_BNFO);
  float* bsum = (float*)(ws + OFF_BSUM);

  fused1_kernel<<<kSampleBlocks + kBboxBlocks + kRandBlocks, 256, 0, stream>>>(
      pred, gt, coords_os, coords_rand, pz, tv, bbp, plp, ccnt);
  fused2_kernel<<<kB * kSLB, 1024, 0, stream>>>(pz, tv, pred, gt, bbp,
                                                osp2, rgp, cand, ccnt, binfo);
  rank_kernel<<<kB, 1024, 0, stream>>>(pz, tv, cand, ccnt, binfo, bsum);
  finalize_kernel<<<1, 64, 0, stream>>>(bsum, osp2, plp, rgp, out);
}